// Round 1
// baseline (547.647 us; speedup 1.0000x reference)
//
#include <hip/hip_runtime.h>
#include <hip/hip_bf16.h>
#include <math.h>

typedef __bf16 bf16;
typedef __bf16 bf16x8 __attribute__((ext_vector_type(8)));
typedef float  f32x4  __attribute__((ext_vector_type(4)));
typedef unsigned int u32;

#define NROWS 16384
#define KDIM  2048
#define NCOLS 2048

// ---------------- workspace layout ----------------
// [0, 64MB)        : x_bf16   (16384*2048*2 = 67108864)
// [64MB, +8MB)     : q_bf16   (2048*2048*2 = 8388608)
// [..., +8MB)      : We_bf16  (8388608)
// [..., +8KB)      : row partial sums of |W| (2048 floats)
// [..., +4B)       : scale
#define OFF_XBF   0
#define OFF_Q     67108864
#define OFF_EBF   75497472
#define OFF_PART  83886080
#define OFF_SCALE 83894272

__device__ __forceinline__ void gload16(const bf16* g, bf16* l) {
    __builtin_amdgcn_global_load_lds(
        (const __attribute__((address_space(1))) u32*)g,
        (__attribute__((address_space(3))) u32*)l,
        16, 0, 0);
}

// ---- 1) per-row sum of |W| (deterministic fixed-order) ----
__global__ void k_rowsum_absW(const float* __restrict__ W, float* __restrict__ partials) {
    int row = blockIdx.x;
    int t = threadIdx.x;
    const float4* wr = (const float4*)(W + (size_t)row * KDIM);
    float4 a = wr[t * 2];
    float4 b = wr[t * 2 + 1];
    float s = fabsf(a.x) + fabsf(a.y) + fabsf(a.z) + fabsf(a.w)
            + fabsf(b.x) + fabsf(b.y) + fabsf(b.z) + fabsf(b.w);
    __shared__ float red[256];
    red[t] = s; __syncthreads();
    for (int off = 128; off > 0; off >>= 1) {
        if (t < off) red[t] += red[t + off];
        __syncthreads();
    }
    if (t == 0) partials[row] = red[0];
}

// ---- 2) finalize scale = max(mean|W|, 1e-8) ----
__global__ void k_scale(const float* __restrict__ partials, float* __restrict__ scale) {
    int t = threadIdx.x;
    double s = 0.0;
    for (int i = t; i < 2048; i += 256) s += (double)partials[i];
    __shared__ double red[256];
    red[t] = s; __syncthreads();
    for (int off = 128; off > 0; off >>= 1) {
        if (t < off) red[t] += red[t + off];
        __syncthreads();
    }
    if (t == 0) {
        float m = (float)(red[0] / 4194304.0);  // 2048*2048
        scale[0] = fmaxf(m, 1e-8f);
    }
}

// ---- 3) ternary-quantize W -> q (bf16 in {-1,0,+1}), cast We -> bf16 ----
__global__ void k_quant(const float* __restrict__ W, const float* __restrict__ We,
                        const float* __restrict__ scale_p,
                        bf16* __restrict__ q, bf16* __restrict__ ebf) {
    float scale = scale_p[0];
    size_t base = ((size_t)blockIdx.x * 256 + threadIdx.x) * 8;
    float4 w0 = *(const float4*)(W + base);
    float4 w1 = *(const float4*)(W + base + 4);
    float4 e0 = *(const float4*)(We + base);
    float4 e1 = *(const float4*)(We + base + 4);
    float wv[8] = {w0.x, w0.y, w0.z, w0.w, w1.x, w1.y, w1.z, w1.w};
    float ev[8] = {e0.x, e0.y, e0.z, e0.w, e1.x, e1.y, e1.z, e1.w};
    bf16x8 qv, bv;
#pragma unroll
    for (int i = 0; i < 8; i++) {
        float ws = wv[i] / scale;
        float qq = ws > 0.3f ? 1.0f : (ws < -0.3f ? -1.0f : 0.0f);
        qv[i] = (bf16)qq;
        bv[i] = (bf16)ev[i];
    }
    *(bf16x8*)(q + base)   = qv;
    *(bf16x8*)(ebf + base) = bv;
}

// ---- 4) x fp32 -> bf16 ----
__global__ void k_cvt_x(const float* __restrict__ x, bf16* __restrict__ xbf) {
    size_t base = ((size_t)blockIdx.x * 256 + threadIdx.x) * 8;
    float4 a = *(const float4*)(x + base);
    float4 c = *(const float4*)(x + base + 4);
    float v[8] = {a.x, a.y, a.z, a.w, c.x, c.y, c.z, c.w};
    bf16x8 o;
#pragma unroll
    for (int i = 0; i < 8; i++) o[i] = (bf16)v[i];
    *(bf16x8*)(xbf + base) = o;
}

// ---- 5) fused dual GEMM: y = relu(scale*(x@q^T) + b) + x@We^T + be ----
#define BM 128
#define BN 128
#define BK 64

__global__ __launch_bounds__(512)
void k_gemm_dual(const bf16* __restrict__ X, const bf16* __restrict__ Q,
                 const bf16* __restrict__ E,
                 const float* __restrict__ b, const float* __restrict__ be,
                 const float* __restrict__ scale_p, float* __restrict__ Y)
{
    __shared__ bf16 lA [BM * BK];
    __shared__ bf16 lB1[BN * BK];
    __shared__ bf16 lB2[BN * BK];

    int t    = threadIdx.x;
    int lane = t & 63;
    int w    = t >> 6;      // 0..7
    int wr   = w >> 2;      // 0..1  (64-row block)
    int wc   = w & 3;       // 0..3  (32-col block)

    int bCol = blockIdx.x;  // 0..15
    int bRow = blockIdx.y;  // 0..127

    const bf16* gA  = X + (size_t)(bRow * BM) * KDIM;
    const bf16* gB1 = Q + (size_t)(bCol * BN) * KDIM;
    const bf16* gB2 = E + (size_t)(bCol * BN) * KDIM;

    int row0 = t >> 3;        // staging row for it=0 (chunk>>3)
    int col0 = (t & 7) * 8;   // staging col (elements)

    f32x4 acc1[4][2], acc2[4][2];
#pragma unroll
    for (int m = 0; m < 4; m++)
#pragma unroll
        for (int n = 0; n < 2; n++) {
            acc1[m][n] = (f32x4){0.f, 0.f, 0.f, 0.f};
            acc2[m][n] = (f32x4){0.f, 0.f, 0.f, 0.f};
        }

    int lrow = lane & 15;
    int lk   = lane >> 4;   // 0..3

    for (int k0 = 0; k0 < KDIM; k0 += BK) {
#pragma unroll
        for (int it = 0; it < 2; ++it) {
            int row = row0 + it * 64;
            int off = (it * 512 + t) * 8;  // element offset into LDS tile
            gload16(gA  + (size_t)row * KDIM + k0 + col0, &lA [off]);
            gload16(gB1 + (size_t)row * KDIM + k0 + col0, &lB1[off]);
            gload16(gB2 + (size_t)row * KDIM + k0 + col0, &lB2[off]);
        }
        __syncthreads();   // drains vmcnt -> staged data visible

#pragma unroll
        for (int kk = 0; kk < 2; kk++) {
            bf16x8 af[4], bq[2], beo[2];
#pragma unroll
            for (int m = 0; m < 4; m++)
                af[m] = *(const bf16x8*)&lA[(wr * 64 + m * 16 + lrow) * BK + kk * 32 + lk * 8];
#pragma unroll
            for (int n = 0; n < 2; n++) {
                bq [n] = *(const bf16x8*)&lB1[(wc * 32 + n * 16 + lrow) * BK + kk * 32 + lk * 8];
                beo[n] = *(const bf16x8*)&lB2[(wc * 32 + n * 16 + lrow) * BK + kk * 32 + lk * 8];
            }
#pragma unroll
            for (int m = 0; m < 4; m++)
#pragma unroll
                for (int n = 0; n < 2; n++) {
                    acc1[m][n] = __builtin_amdgcn_mfma_f32_16x16x32_bf16(af[m], bq [n], acc1[m][n], 0, 0, 0);
                    acc2[m][n] = __builtin_amdgcn_mfma_f32_16x16x32_bf16(af[m], beo[n], acc2[m][n], 0, 0, 0);
                }
        }
        __syncthreads();
    }

    float scale = scale_p[0];
    // C/D layout (16x16x32): col = lane&15, row = (lane>>4)*4 + reg
#pragma unroll
    for (int m = 0; m < 4; m++) {
        int gr0 = bRow * BM + wr * 64 + m * 16 + (lane >> 4) * 4;
#pragma unroll
        for (int n = 0; n < 2; n++) {
            int gc = bCol * BN + wc * 32 + n * 16 + (lane & 15);
            float bj  = b[gc];
            float bej = be[gc];
#pragma unroll
            for (int v = 0; v < 4; v++) {
                float chain = fmaxf(acc1[m][n][v] * scale + bj, 0.0f);
                float y = chain + acc2[m][n][v] + bej;
                Y[(size_t)(gr0 + v) * NCOLS + gc] = y;
            }
        }
    }
}

// ---- 6) per-row fake-int8 quantization, in place on d_out ----
__global__ void k_quant_rows(float* __restrict__ Y) {
    int row = blockIdx.x;
    int t = threadIdx.x;
    float4* yv = (float4*)(Y + (size_t)row * NCOLS);
    float4 a = yv[t];
    float4 c = yv[t + 256];
    float mx = fmaxf(fmaxf(fmaxf(fabsf(a.x), fabsf(a.y)), fmaxf(fabsf(a.z), fabsf(a.w))),
                     fmaxf(fmaxf(fabsf(c.x), fabsf(c.y)), fmaxf(fabsf(c.z), fabsf(c.w))));
    __shared__ float red[256];
    red[t] = mx; __syncthreads();
    for (int off = 128; off > 0; off >>= 1) {
        if (t < off) red[t] = fmaxf(red[t], red[t + off]);
        __syncthreads();
    }
    float m = fmaxf(red[0], 1e-5f);
    float qs = 127.0f / m;
    float4 oa, oc;
    oa.x = rintf(fminf(fmaxf(a.x * qs, -127.f), 127.f)) / qs;
    oa.y = rintf(fminf(fmaxf(a.y * qs, -127.f), 127.f)) / qs;
    oa.z = rintf(fminf(fmaxf(a.z * qs, -127.f), 127.f)) / qs;
    oa.w = rintf(fminf(fmaxf(a.w * qs, -127.f), 127.f)) / qs;
    oc.x = rintf(fminf(fmaxf(c.x * qs, -127.f), 127.f)) / qs;
    oc.y = rintf(fminf(fmaxf(c.y * qs, -127.f), 127.f)) / qs;
    oc.z = rintf(fminf(fmaxf(c.z * qs, -127.f), 127.f)) / qs;
    oc.w = rintf(fminf(fmaxf(c.w * qs, -127.f), 127.f)) / qs;
    yv[t] = oa;
    yv[t + 256] = oc;
}

extern "C" void kernel_launch(void* const* d_in, const int* in_sizes, int n_in,
                              void* d_out, int out_size, void* d_ws, size_t ws_size,
                              hipStream_t stream) {
    const float* x  = (const float*)d_in[0];
    const float* W  = (const float*)d_in[1];
    const float* b  = (const float*)d_in[2];
    const float* We = (const float*)d_in[3];
    const float* be = (const float*)d_in[4];
    float* out = (float*)d_out;

    char* ws = (char*)d_ws;
    bf16*  xbf      = (bf16*)(ws + OFF_XBF);
    bf16*  q        = (bf16*)(ws + OFF_Q);
    bf16*  ebf      = (bf16*)(ws + OFF_EBF);
    float* partials = (float*)(ws + OFF_PART);
    float* scale    = (float*)(ws + OFF_SCALE);

    k_rowsum_absW<<<2048, 256, 0, stream>>>(W, partials);
    k_scale<<<1, 256, 0, stream>>>(partials, scale);
    k_quant<<<2048, 256, 0, stream>>>(W, We, scale, q, ebf);
    k_cvt_x<<<16384, 256, 0, stream>>>(x, xbf);

    dim3 g(NCOLS / BN, NROWS / BM);   // (16, 128)
    k_gemm_dual<<<g, 512, 0, stream>>>(xbf, q, ebf, b, be, scale, out);

    k_quant_rows<<<NROWS, 256, 0, stream>>>(out);
}

// Round 2
// 317.663 us; speedup vs baseline: 1.7240x; 1.7240x over previous
//
#include <hip/hip_runtime.h>
#include <hip/hip_bf16.h>
#include <math.h>

typedef __bf16 bf16;
typedef __bf16 bf16x8 __attribute__((ext_vector_type(8)));
typedef float  f32x4  __attribute__((ext_vector_type(4)));
typedef unsigned int u32;

#define NROWS 16384
#define KDIM  2048
#define NCOLS 2048

// ---------------- workspace layout ----------------
#define OFF_XBF   0
#define OFF_Q     67108864
#define OFF_EBF   75497472
#define OFF_PART  83886080
#define OFF_SCALE 83894272

__device__ __forceinline__ void gload16(const bf16* g, bf16* l) {
    __builtin_amdgcn_global_load_lds(
        (const __attribute__((address_space(1))) u32*)g,
        (__attribute__((address_space(3))) u32*)l,
        16, 0, 0);
}

// ---- 1) per-row sum of |W| (deterministic fixed-order) ----
__global__ void k_rowsum_absW(const float* __restrict__ W, float* __restrict__ partials) {
    int row = blockIdx.x;
    int t = threadIdx.x;
    const float4* wr = (const float4*)(W + (size_t)row * KDIM);
    float4 a = wr[t * 2];
    float4 b = wr[t * 2 + 1];
    float s = fabsf(a.x) + fabsf(a.y) + fabsf(a.z) + fabsf(a.w)
            + fabsf(b.x) + fabsf(b.y) + fabsf(b.z) + fabsf(b.w);
    __shared__ float red[256];
    red[t] = s; __syncthreads();
    for (int off = 128; off > 0; off >>= 1) {
        if (t < off) red[t] += red[t + off];
        __syncthreads();
    }
    if (t == 0) partials[row] = red[0];
}

// ---- 2) finalize scale = max(mean|W|, 1e-8) ----
__global__ void k_scale(const float* __restrict__ partials, float* __restrict__ scale) {
    int t = threadIdx.x;
    double s = 0.0;
    for (int i = t; i < 2048; i += 256) s += (double)partials[i];
    __shared__ double red[256];
    red[t] = s; __syncthreads();
    for (int off = 128; off > 0; off >>= 1) {
        if (t < off) red[t] += red[t + off];
        __syncthreads();
    }
    if (t == 0) {
        float m = (float)(red[0] / 4194304.0);  // 2048*2048
        scale[0] = fmaxf(m, 1e-8f);
    }
}

// ---- 3) ternary-quantize W -> q (bf16 in {-1,0,+1}), cast We -> bf16 ----
__global__ void k_quant(const float* __restrict__ W, const float* __restrict__ We,
                        const float* __restrict__ scale_p,
                        bf16* __restrict__ q, bf16* __restrict__ ebf) {
    float scale = scale_p[0];
    size_t base = ((size_t)blockIdx.x * 256 + threadIdx.x) * 8;
    float4 w0 = *(const float4*)(W + base);
    float4 w1 = *(const float4*)(W + base + 4);
    float4 e0 = *(const float4*)(We + base);
    float4 e1 = *(const float4*)(We + base + 4);
    float wv[8] = {w0.x, w0.y, w0.z, w0.w, w1.x, w1.y, w1.z, w1.w};
    float ev[8] = {e0.x, e0.y, e0.z, e0.w, e1.x, e1.y, e1.z, e1.w};
    bf16x8 qv, bv;
#pragma unroll
    for (int i = 0; i < 8; i++) {
        float ws = wv[i] / scale;
        float qq = ws > 0.3f ? 1.0f : (ws < -0.3f ? -1.0f : 0.0f);
        qv[i] = (bf16)qq;
        bv[i] = (bf16)ev[i];
    }
    *(bf16x8*)(q + base)   = qv;
    *(bf16x8*)(ebf + base) = bv;
}

// ---- 4) x fp32 -> bf16 ----
__global__ void k_cvt_x(const float* __restrict__ x, bf16* __restrict__ xbf) {
    size_t base = ((size_t)blockIdx.x * 256 + threadIdx.x) * 8;
    float4 a = *(const float4*)(x + base);
    float4 c = *(const float4*)(x + base + 4);
    float v[8] = {a.x, a.y, a.z, a.w, c.x, c.y, c.z, c.w};
    bf16x8 o;
#pragma unroll
    for (int i = 0; i < 8; i++) o[i] = (bf16)v[i];
    *(bf16x8*)(xbf + base) = o;
}

// ---- 5) fused dual GEMM: y = relu(scale*(x@q^T) + b) + x@We^T + be ----
// LDS tiles are XOR-swizzled (T2, st-style): physical elem = row*64 + (col ^ ((row&7)<<3)).
// global_load_lds writes linearly, so the SOURCE global column is pre-swizzled
// (rule #21: linear dest + inverse-swz source + swz on read; XOR is an involution).
#define BM 128
#define BN 128
#define BK 64

__global__ __launch_bounds__(512)
void k_gemm_dual(const bf16* __restrict__ X, const bf16* __restrict__ Q,
                 const bf16* __restrict__ E,
                 const float* __restrict__ b, const float* __restrict__ be,
                 const float* __restrict__ scale_p, float* __restrict__ Y)
{
    __shared__ bf16 lA [BM * BK];
    __shared__ bf16 lB1[BN * BK];
    __shared__ bf16 lB2[BN * BK];

    int t    = threadIdx.x;
    int lane = t & 63;
    int w    = t >> 6;      // 0..7
    int wr   = w >> 2;      // 0..1  (64-row block)
    int wc   = w & 3;       // 0..3  (32-col block)

    int bCol = blockIdx.x;  // 0..15
    int bRow = blockIdx.y;  // 0..127

    const bf16* gA  = X + (size_t)(bRow * BM) * KDIM;
    const bf16* gB1 = Q + (size_t)(bCol * BN) * KDIM;
    const bf16* gB2 = E + (size_t)(bCol * BN) * KDIM;

    int row0 = t >> 3;                       // staging row for it=0
    // pre-swizzled global source column (elements):
    int colsw = ((t & 7) * 8) ^ ((row0 & 7) << 3);

    f32x4 acc1[4][2], acc2[4][2];
#pragma unroll
    for (int m = 0; m < 4; m++)
#pragma unroll
        for (int n = 0; n < 2; n++) {
            acc1[m][n] = (f32x4){0.f, 0.f, 0.f, 0.f};
            acc2[m][n] = (f32x4){0.f, 0.f, 0.f, 0.f};
        }

    int lrow = lane & 15;
    int lk   = lane >> 4;   // 0..3

    for (int k0 = 0; k0 < KDIM; k0 += BK) {
#pragma unroll
        for (int it = 0; it < 2; ++it) {
            int row = row0 + it * 64;        // (it*64 doesn't change row&7)
            int off = (it * 512 + t) * 8;    // linear LDS dest (elements)
            gload16(gA  + (size_t)row * KDIM + k0 + colsw, &lA [off]);
            gload16(gB1 + (size_t)row * KDIM + k0 + colsw, &lB1[off]);
            gload16(gB2 + (size_t)row * KDIM + k0 + colsw, &lB2[off]);
        }
        __syncthreads();   // drains vmcnt -> staged data visible

#pragma unroll
        for (int kk = 0; kk < 2; kk++) {
            int ko = kk * 32 + lk * 8;       // logical k-offset (elements)
            bf16x8 af[4], bq[2], beo[2];
#pragma unroll
            for (int m = 0; m < 4; m++) {
                int ar = wr * 64 + m * 16 + lrow;
                af[m] = *(const bf16x8*)&lA[ar * BK + (ko ^ ((ar & 7) << 3))];
            }
#pragma unroll
            for (int n = 0; n < 2; n++) {
                int br = wc * 32 + n * 16 + lrow;
                int sc = ko ^ ((br & 7) << 3);
                bq [n] = *(const bf16x8*)&lB1[br * BK + sc];
                beo[n] = *(const bf16x8*)&lB2[br * BK + sc];
            }
#pragma unroll
            for (int m = 0; m < 4; m++)
#pragma unroll
                for (int n = 0; n < 2; n++) {
                    acc1[m][n] = __builtin_amdgcn_mfma_f32_16x16x32_bf16(af[m], bq [n], acc1[m][n], 0, 0, 0);
                    acc2[m][n] = __builtin_amdgcn_mfma_f32_16x16x32_bf16(af[m], beo[n], acc2[m][n], 0, 0, 0);
                }
        }
        __syncthreads();
    }

    float scale = scale_p[0];
    // C/D layout (16x16x32): col = lane&15, row = (lane>>4)*4 + reg
#pragma unroll
    for (int m = 0; m < 4; m++) {
        int gr0 = bRow * BM + wr * 64 + m * 16 + (lane >> 4) * 4;
#pragma unroll
        for (int n = 0; n < 2; n++) {
            int gc = bCol * BN + wc * 32 + n * 16 + (lane & 15);
            float bj  = b[gc];
            float bej = be[gc];
#pragma unroll
            for (int v = 0; v < 4; v++) {
                float chain = fmaxf(acc1[m][n][v] * scale + bj, 0.0f);
                float y = chain + acc2[m][n][v] + bej;
                Y[(size_t)(gr0 + v) * NCOLS + gc] = y;
            }
        }
    }
}

// ---- 6) per-row fake-int8 quantization, in place on d_out ----
__global__ void k_quant_rows(float* __restrict__ Y) {
    int row = blockIdx.x;
    int t = threadIdx.x;
    float4* yv = (float4*)(Y + (size_t)row * NCOLS);
    float4 a = yv[t];
    float4 c = yv[t + 256];
    float mx = fmaxf(fmaxf(fmaxf(fabsf(a.x), fabsf(a.y)), fmaxf(fabsf(a.z), fabsf(a.w))),
                     fmaxf(fmaxf(fabsf(c.x), fabsf(c.y)), fmaxf(fabsf(c.z), fabsf(c.w))));
    __shared__ float red[256];
    red[t] = mx; __syncthreads();
    for (int off = 128; off > 0; off >>= 1) {
        if (t < off) red[t] = fmaxf(red[t], red[t + off]);
        __syncthreads();
    }
    float m = fmaxf(red[0], 1e-5f);
    float qs = 127.0f / m;
    float4 oa, oc;
    oa.x = rintf(fminf(fmaxf(a.x * qs, -127.f), 127.f)) / qs;
    oa.y = rintf(fminf(fmaxf(a.y * qs, -127.f), 127.f)) / qs;
    oa.z = rintf(fminf(fmaxf(a.z * qs, -127.f), 127.f)) / qs;
    oa.w = rintf(fminf(fmaxf(a.w * qs, -127.f), 127.f)) / qs;
    oc.x = rintf(fminf(fmaxf(c.x * qs, -127.f), 127.f)) / qs;
    oc.y = rintf(fminf(fmaxf(c.y * qs, -127.f), 127.f)) / qs;
    oc.z = rintf(fminf(fmaxf(c.z * qs, -127.f), 127.f)) / qs;
    oc.w = rintf(fminf(fmaxf(c.w * qs, -127.f), 127.f)) / qs;
    yv[t] = oa;
    yv[t + 256] = oc;
}

extern "C" void kernel_launch(void* const* d_in, const int* in_sizes, int n_in,
                              void* d_out, int out_size, void* d_ws, size_t ws_size,
                              hipStream_t stream) {
    const float* x  = (const float*)d_in[0];
    const float* W  = (const float*)d_in[1];
    const float* b  = (const float*)d_in[2];
    const float* We = (const float*)d_in[3];
    const float* be = (const float*)d_in[4];
    float* out = (float*)d_out;

    char* ws = (char*)d_ws;
    bf16*  xbf      = (bf16*)(ws + OFF_XBF);
    bf16*  q        = (bf16*)(ws + OFF_Q);
    bf16*  ebf      = (bf16*)(ws + OFF_EBF);
    float* partials = (float*)(ws + OFF_PART);
    float* scale    = (float*)(ws + OFF_SCALE);

    k_rowsum_absW<<<2048, 256, 0, stream>>>(W, partials);
    k_scale<<<1, 256, 0, stream>>>(partials, scale);
    k_quant<<<2048, 256, 0, stream>>>(W, We, scale, q, ebf);
    k_cvt_x<<<16384, 256, 0, stream>>>(x, xbf);

    dim3 g(NCOLS / BN, NROWS / BM);   // (16, 128)
    k_gemm_dual<<<g, 512, 0, stream>>>(xbf, q, ebf, b, be, scale, out);

    k_quant_rows<<<NROWS, 256, 0, stream>>>(out);
}

// Round 3
// 311.429 us; speedup vs baseline: 1.7585x; 1.0200x over previous
//
#include <hip/hip_runtime.h>
#include <hip/hip_bf16.h>
#include <math.h>

typedef __bf16 bf16;
typedef __bf16 bf16x8 __attribute__((ext_vector_type(8)));
typedef float  f32x4  __attribute__((ext_vector_type(4)));
typedef unsigned int u32;

#define NROWS 16384
#define KDIM  2048
#define NCOLS 2048

// ---------------- workspace layout ----------------
#define OFF_XBF   0
#define OFF_Q     67108864
#define OFF_EBF   75497472
#define OFF_PART  83886080
#define OFF_SCALE 83894272

__device__ __forceinline__ void gload16(const bf16* g, bf16* l) {
    __builtin_amdgcn_global_load_lds(
        (const __attribute__((address_space(1))) u32*)g,
        (__attribute__((address_space(3))) u32*)l,
        16, 0, 0);
}

// ---- 1) per-row sum of |W| (deterministic fixed-order) ----
__global__ void k_rowsum_absW(const float* __restrict__ W, float* __restrict__ partials) {
    int row = blockIdx.x;
    int t = threadIdx.x;
    const float4* wr = (const float4*)(W + (size_t)row * KDIM);
    float4 a = wr[t * 2];
    float4 b = wr[t * 2 + 1];
    float s = fabsf(a.x) + fabsf(a.y) + fabsf(a.z) + fabsf(a.w)
            + fabsf(b.x) + fabsf(b.y) + fabsf(b.z) + fabsf(b.w);
    __shared__ float red[256];
    red[t] = s; __syncthreads();
    for (int off = 128; off > 0; off >>= 1) {
        if (t < off) red[t] += red[t + off];
        __syncthreads();
    }
    if (t == 0) partials[row] = red[0];
}

// ---- 2) finalize scale = max(mean|W|, 1e-8) ----
__global__ void k_scale(const float* __restrict__ partials, float* __restrict__ scale) {
    int t = threadIdx.x;
    double s = 0.0;
    for (int i = t; i < 2048; i += 256) s += (double)partials[i];
    __shared__ double red[256];
    red[t] = s; __syncthreads();
    for (int off = 128; off > 0; off >>= 1) {
        if (t < off) red[t] += red[t + off];
        __syncthreads();
    }
    if (t == 0) {
        float m = (float)(red[0] / 4194304.0);  // 2048*2048
        scale[0] = fmaxf(m, 1e-8f);
    }
}

// ---- 3) ternary-quantize W -> q (bf16 in {-1,0,+1}), cast We -> bf16 ----
__global__ void k_quant(const float* __restrict__ W, const float* __restrict__ We,
                        const float* __restrict__ scale_p,
                        bf16* __restrict__ q, bf16* __restrict__ ebf) {
    float scale = scale_p[0];
    size_t base = ((size_t)blockIdx.x * 256 + threadIdx.x) * 8;
    float4 w0 = *(const float4*)(W + base);
    float4 w1 = *(const float4*)(W + base + 4);
    float4 e0 = *(const float4*)(We + base);
    float4 e1 = *(const float4*)(We + base + 4);
    float wv[8] = {w0.x, w0.y, w0.z, w0.w, w1.x, w1.y, w1.z, w1.w};
    float ev[8] = {e0.x, e0.y, e0.z, e0.w, e1.x, e1.y, e1.z, e1.w};
    bf16x8 qv, bv;
#pragma unroll
    for (int i = 0; i < 8; i++) {
        float ws = wv[i] / scale;
        float qq = ws > 0.3f ? 1.0f : (ws < -0.3f ? -1.0f : 0.0f);
        qv[i] = (bf16)qq;
        bv[i] = (bf16)ev[i];
    }
    *(bf16x8*)(q + base)   = qv;
    *(bf16x8*)(ebf + base) = bv;
}

// ---- 4) x fp32 -> bf16 ----
__global__ void k_cvt_x(const float* __restrict__ x, bf16* __restrict__ xbf) {
    size_t base = ((size_t)blockIdx.x * 256 + threadIdx.x) * 8;
    float4 a = *(const float4*)(x + base);
    float4 c = *(const float4*)(x + base + 4);
    float v[8] = {a.x, a.y, a.z, a.w, c.x, c.y, c.z, c.w};
    bf16x8 o;
#pragma unroll
    for (int i = 0; i < 8; i++) o[i] = (bf16)v[i];
    *(bf16x8*)(xbf + base) = o;
}

// ---- 5) fused dual GEMM: y = relu(scale*(x@q^T) + b) + x@We^T + be ----
// 4 waves (256 thr), each owning a 64x64 output tile (m=n=4 of 16x16),
// dual accumulators sharing the A fragments. LDS XOR-swizzled (T2):
// physical elem = row*64 + (col ^ ((row&7)<<3)); global_load_lds writes
// linearly so the global SOURCE column is pre-swizzled (rule #21).
#define BM 128
#define BN 128
#define BK 64

__global__ __launch_bounds__(256, 2)
void k_gemm_dual(const bf16* __restrict__ X, const bf16* __restrict__ Q,
                 const bf16* __restrict__ E,
                 const float* __restrict__ b, const float* __restrict__ be,
                 const float* __restrict__ scale_p, float* __restrict__ Y)
{
    __shared__ bf16 lA [BM * BK];
    __shared__ bf16 lB1[BN * BK];
    __shared__ bf16 lB2[BN * BK];

    int t    = threadIdx.x;
    int lane = t & 63;
    int w    = t >> 6;      // 0..3
    int wr   = w >> 1;      // 0..1  (64-row block)
    int wc   = w & 1;       // 0..1  (64-col block)

    int bCol = blockIdx.x;  // 0..15
    int bRow = blockIdx.y;  // 0..127

    const bf16* gA  = X + (size_t)(bRow * BM) * KDIM;
    const bf16* gB1 = Q + (size_t)(bCol * BN) * KDIM;
    const bf16* gB2 = E + (size_t)(bCol * BN) * KDIM;

    int row0 = t >> 3;                       // staging row for it=0 (0..31)
    // pre-swizzled global source column (elements):
    int colsw = ((t & 7) * 8) ^ ((row0 & 7) << 3);

    f32x4 acc1[4][4], acc2[4][4];
#pragma unroll
    for (int m = 0; m < 4; m++)
#pragma unroll
        for (int n = 0; n < 4; n++) {
            acc1[m][n] = (f32x4){0.f, 0.f, 0.f, 0.f};
            acc2[m][n] = (f32x4){0.f, 0.f, 0.f, 0.f};
        }

    int lrow = lane & 15;
    int lk   = lane >> 4;   // 0..3

    for (int k0 = 0; k0 < KDIM; k0 += BK) {
#pragma unroll
        for (int it = 0; it < 4; ++it) {
            int row = row0 + it * 32;        // (it*32 doesn't change row&7)
            int off = (it * 256 + t) * 8;    // linear LDS dest (elements)
            gload16(gA  + (size_t)row * KDIM + k0 + colsw, &lA [off]);
            gload16(gB1 + (size_t)row * KDIM + k0 + colsw, &lB1[off]);
            gload16(gB2 + (size_t)row * KDIM + k0 + colsw, &lB2[off]);
        }
        __syncthreads();   // drains vmcnt -> staged data visible

#pragma unroll
        for (int kk = 0; kk < 2; kk++) {
            int ko = kk * 32 + lk * 8;       // logical k-offset (elements)
            bf16x8 af[4], bq[4], beo[4];
#pragma unroll
            for (int m = 0; m < 4; m++) {
                int ar = wr * 64 + m * 16 + lrow;
                af[m] = *(const bf16x8*)&lA[ar * BK + (ko ^ ((ar & 7) << 3))];
            }
#pragma unroll
            for (int n = 0; n < 4; n++) {
                int br = wc * 64 + n * 16 + lrow;
                int sc = ko ^ ((br & 7) << 3);
                bq [n] = *(const bf16x8*)&lB1[br * BK + sc];
                beo[n] = *(const bf16x8*)&lB2[br * BK + sc];
            }
#pragma unroll
            for (int m = 0; m < 4; m++)
#pragma unroll
                for (int n = 0; n < 4; n++) {
                    acc1[m][n] = __builtin_amdgcn_mfma_f32_16x16x32_bf16(af[m], bq [n], acc1[m][n], 0, 0, 0);
                    acc2[m][n] = __builtin_amdgcn_mfma_f32_16x16x32_bf16(af[m], beo[n], acc2[m][n], 0, 0, 0);
                }
        }
        __syncthreads();
    }

    float scale = scale_p[0];
    // C/D layout (16x16x32): col = lane&15, row = (lane>>4)*4 + reg
#pragma unroll
    for (int m = 0; m < 4; m++) {
        int gr0 = bRow * BM + wr * 64 + m * 16 + (lane >> 4) * 4;
#pragma unroll
        for (int n = 0; n < 4; n++) {
            int gc = bCol * BN + wc * 64 + n * 16 + (lane & 15);
            float bj  = b[gc];
            float bej = be[gc];
#pragma unroll
            for (int v = 0; v < 4; v++) {
                float chain = fmaxf(acc1[m][n][v] * scale + bj, 0.0f);
                float y = chain + acc2[m][n][v] + bej;
                Y[(size_t)(gr0 + v) * NCOLS + gc] = y;
            }
        }
    }
}

// ---- 6) per-row fake-int8 quantization, in place on d_out ----
__global__ void k_quant_rows(float* __restrict__ Y) {
    int row = blockIdx.x;
    int t = threadIdx.x;
    float4* yv = (float4*)(Y + (size_t)row * NCOLS);
    float4 a = yv[t];
    float4 c = yv[t + 256];
    float mx = fmaxf(fmaxf(fmaxf(fabsf(a.x), fabsf(a.y)), fmaxf(fabsf(a.z), fabsf(a.w))),
                     fmaxf(fmaxf(fabsf(c.x), fabsf(c.y)), fmaxf(fabsf(c.z), fabsf(c.w))));
    __shared__ float red[256];
    red[t] = mx; __syncthreads();
    for (int off = 128; off > 0; off >>= 1) {
        if (t < off) red[t] = fmaxf(red[t], red[t + off]);
        __syncthreads();
    }
    float m = fmaxf(red[0], 1e-5f);
    float qs = 127.0f / m;
    float4 oa, oc;
    oa.x = rintf(fminf(fmaxf(a.x * qs, -127.f), 127.f)) / qs;
    oa.y = rintf(fminf(fmaxf(a.y * qs, -127.f), 127.f)) / qs;
    oa.z = rintf(fminf(fmaxf(a.z * qs, -127.f), 127.f)) / qs;
    oa.w = rintf(fminf(fmaxf(a.w * qs, -127.f), 127.f)) / qs;
    oc.x = rintf(fminf(fmaxf(c.x * qs, -127.f), 127.f)) / qs;
    oc.y = rintf(fminf(fmaxf(c.y * qs, -127.f), 127.f)) / qs;
    oc.z = rintf(fminf(fmaxf(c.z * qs, -127.f), 127.f)) / qs;
    oc.w = rintf(fminf(fmaxf(c.w * qs, -127.f), 127.f)) / qs;
    yv[t] = oa;
    yv[t + 256] = oc;
}

extern "C" void kernel_launch(void* const* d_in, const int* in_sizes, int n_in,
                              void* d_out, int out_size, void* d_ws, size_t ws_size,
                              hipStream_t stream) {
    const float* x  = (const float*)d_in[0];
    const float* W  = (const float*)d_in[1];
    const float* b  = (const float*)d_in[2];
    const float* We = (const float*)d_in[3];
    const float* be = (const float*)d_in[4];
    float* out = (float*)d_out;

    char* ws = (char*)d_ws;
    bf16*  xbf      = (bf16*)(ws + OFF_XBF);
    bf16*  q        = (bf16*)(ws + OFF_Q);
    bf16*  ebf      = (bf16*)(ws + OFF_EBF);
    float* partials = (float*)(ws + OFF_PART);
    float* scale    = (float*)(ws + OFF_SCALE);

    k_rowsum_absW<<<2048, 256, 0, stream>>>(W, partials);
    k_scale<<<1, 256, 0, stream>>>(partials, scale);
    k_quant<<<2048, 256, 0, stream>>>(W, We, scale, q, ebf);
    k_cvt_x<<<16384, 256, 0, stream>>>(x, xbf);

    dim3 g(NCOLS / BN, NROWS / BM);   // (16, 128)
    k_gemm_dual<<<g, 256, 0, stream>>>(xbf, q, ebf, b, be, scale, out);

    k_quant_rows<<<NROWS, 256, 0, stream>>>(out);
}